// Round 3
// baseline (1137.536 us; speedup 1.0000x reference)
//
#include <hip/hip_runtime.h>
#include <hip/hip_bf16.h>

#define HH 448
#define WW 160
#define NPIX (HH*WW)

typedef unsigned long long u64;

__device__ __forceinline__ float leaky(float v) { return v >= 0.f ? v : 0.01f * v; }

// act stored transposed: logical (w, c) -> float index with XOR block swizzle.
// Row = 128 floats (32 x 16B blocks); physical block = (c/4) ^ (w & 31).
__device__ __forceinline__ int actIdx(int w, int c) {
    return (w << 7) + ((((c >> 2) ^ (w & 31))) << 2) + (c & 3);
}

// One tile: 8 rows (rg*8..+7) x 1 col per lane, full K=128.
// x: 1 swizzled ds_read_b128 per cb (lanes pairwise-identical addrs -> free 2-way merge).
// W: 8 global_load_dwordx4 per cb, half-wave-uniform addrs (2 transactions/instr),
//    all offsets fit base+imm13 -> deep compiler pipelining.
// FMA order: ascending c (cb asc, .x..w asc) — bitwise-matches the verified kernel.
__device__ __forceinline__ void computeTile(const float* act, const float* __restrict__ wp,
                                            int col, float acc[8])
{
    const int cbase = col << 7;
    const int ck = col & 31;
#pragma unroll
    for (int a = 0; a < 8; ++a) acc[a] = 0.f;
#pragma unroll 4
    for (int cb = 0; cb < 32; ++cb) {
        const float4 xv = *reinterpret_cast<const float4*>(act + cbase + ((cb ^ ck) << 2));
#pragma unroll
        for (int a = 0; a < 8; ++a) {
            const float4 wv = *reinterpret_cast<const float4*>(wp + a * 128 + cb * 4);
            acc[a] = fmaf(wv.x, xv.x, acc[a]);
            acc[a] = fmaf(wv.y, xv.y, acc[a]);
            acc[a] = fmaf(wv.z, xv.z, acc[a]);
            acc[a] = fmaf(wv.w, xv.w, acc[a]);
        }
    }
}

__global__ __launch_bounds__(512, 2) void kA(
    const float* __restrict__ x_in,
    const float* __restrict__ Wcl1, const float* __restrict__ bcl1,
    const float* __restrict__ Wcl2, const float* __restrict__ bcl2,
    const float* __restrict__ Wcl3, const float* __restrict__ bcl3,
    const float* __restrict__ Wcl4, const float* __restrict__ bcl4,
    const float* __restrict__ Wreg1, const float* __restrict__ breg1,
    __hip_bfloat16* __restrict__ xr, int* __restrict__ ind, float* __restrict__ out)
{
    __shared__ float act[WW * 128];   // 80 KB swizzled transposed activations (in-place)
    __shared__ u64 argb[WW];          // packed (value, 255-idx) argmax

    const int h = blockIdx.x;
    const int t = threadIdx.x;
    const int wave = t >> 6;          // 0..7
    const int half = (t >> 5) & 1;    // rg-pair half
    const int lc = t & 31;            // col within 32-strip

    if (t < WW) argb[t] = 0ull;

    // ---- stage x: global [c][h][w] -> act (transpose + swizzle) ----
    {
        const float4* xg = reinterpret_cast<const float4*>(x_in);
#pragma unroll
        for (int k = 0; k < 10; ++k) {
            const int fi = t + (k << 9);          // 0..5119 float4s
            const int c = fi / 40, wq = fi - c * 40;
            const float4 v = xg[((size_t)c * HH + h) * 40 + wq];
            const int w0 = wq << 2;
            act[actIdx(w0 + 0, c)] = v.x;
            act[actIdx(w0 + 1, c)] = v.y;
            act[actIdx(w0 + 2, c)] = v.z;
            act[actIdx(w0 + 3, c)] = v.w;
        }
    }
    __syncthreads();

    // ---- reg1: 256 rows = 16 rg-pairs x 5 strips = 80 tiles, 10/wave. No act writes. ----
    {
        const float* W1 = Wreg1 + (size_t)h * (256 * 128);
        const float* b1 = breg1 + h * 256;
#pragma unroll 1
        for (int i = 0; i < 10; ++i) {
            const int id = wave * 10 + i;
            const int s = id >> 4, p = id & 15;
            const int rg = 2 * p + half;
            const int col = (s << 5) + lc;
            float acc[8];
            computeTile(act, W1 + rg * 1024, col, acc);
            const float* bp = b1 + rg * 8;
            alignas(16) unsigned short us[8];
#pragma unroll
            for (int a = 0; a < 8; ++a) {
                __hip_bfloat16 bv = __float2bfloat16(leaky(acc[a] + bp[a]));
                us[a] = *reinterpret_cast<const unsigned short*>(&bv);
            }
            *reinterpret_cast<uint4*>(xr + (((size_t)(h * WW + col)) << 8) + rg * 8) =
                *reinterpret_cast<const uint4*>(us);
        }
    }

    // ---- cl1..cl3: 8 rg-pairs x 5 strips = 40 tiles, 5/wave; hold acc across barrier ----
#pragma unroll 1
    for (int L = 0; L < 3; ++L) {
        const float* W = (L == 0) ? Wcl1 + (size_t)h * 16384
                       : (L == 1) ? Wcl2 + (size_t)h * 16384
                                  : Wcl3 + (size_t)h * 16384;
        const float* b = (L == 0) ? bcl1 + (h << 7)
                       : (L == 1) ? bcl2 + (h << 7)
                                  : bcl3 + (h << 7);
        float accs[5][8];
#pragma unroll
        for (int i = 0; i < 5; ++i) {
            const int id = wave * 5 + i;
            const int s = id >> 3, p = id & 7;
            const int rg = 2 * p + half;
            const int col = (s << 5) + lc;
            computeTile(act, W + rg * 1024, col, accs[i]);
        }
        __syncthreads();               // all act reads done
#pragma unroll
        for (int i = 0; i < 5; ++i) {
            const int id = wave * 5 + i;
            const int s = id >> 3, p = id & 7;
            const int rg = 2 * p + half;
            const int col = (s << 5) + lc;
            const float* bp = b + rg * 8;
            float4 lo, hi;
            lo.x = leaky(accs[i][0] + bp[0]); lo.y = leaky(accs[i][1] + bp[1]);
            lo.z = leaky(accs[i][2] + bp[2]); lo.w = leaky(accs[i][3] + bp[3]);
            hi.x = leaky(accs[i][4] + bp[4]); hi.y = leaky(accs[i][5] + bp[5]);
            hi.z = leaky(accs[i][6] + bp[6]); hi.w = leaky(accs[i][7] + bp[7]);
            const int ck = col & 31;
            *reinterpret_cast<float4*>(act + (col << 7) + (((rg * 2    ) ^ ck) << 2)) = lo;
            *reinterpret_cast<float4*>(act + (col << 7) + (((rg * 2 + 1) ^ ck) << 2)) = hi;
        }
        __syncthreads();
    }

    // ---- cl4: 256 class rows = 80 tiles, 10/wave; argmax only, col-stable strip order ----
    {
        const float* W4 = Wcl4 + (size_t)h * (257 * 128);
        const float* b4 = bcl4 + h * 257;
        float mv = -3.4e38f;
        int mr = 0;
        int cur_s = -1;
#pragma unroll 1
        for (int i = 0; i < 10; ++i) {
            const int id = wave * 10 + i;
            const int s = id >> 4, p = id & 15;
            const int rg = 2 * p + half;
            const int col = (s << 5) + lc;
            if (s != cur_s) {
                if (cur_s >= 0) {
                    unsigned u = __float_as_uint(mv);
                    u = (u & 0x80000000u) ? ~u : (u | 0x80000000u);
                    atomicMax(&argb[(cur_s << 5) + lc],
                              ((u64)u << 32) | (unsigned)(255 - mr));
                }
                cur_s = s; mv = -3.4e38f; mr = 0;
            }
            float acc[8];
            computeTile(act, W4 + rg * 1024, col, acc);
            const float* bp = b4 + rg * 8;
#pragma unroll
            for (int a = 0; a < 8; ++a) {
                const float v = acc[a] + bp[a];     // rows ascending per lane (p asc)
                if (v > mv) { mv = v; mr = rg * 8 + a; }
            }
        }
        {
            unsigned u = __float_as_uint(mv);
            u = (u & 0x80000000u) ? ~u : (u | 0x80000000u);
            atomicMax(&argb[(cur_s << 5) + lc], ((u64)u << 32) | (unsigned)(255 - mr));
        }
    }
    __syncthreads();

    // ---- finalize: ind + mask row (act still holds cl3 output) ----
    if (t < WW) {
        const u64 k = argb[t];
        const int idx = 255 - (int)(k & 0xFFu);
        ind[h * WW + t] = idx;
        const float* Wm = Wcl4 + ((size_t)h * 257 + 256) * 128;
        const int ck = t & 31;
        float accm = 0.f;
#pragma unroll 4
        for (int cb = 0; cb < 32; ++cb) {
            const float4 xv = *reinterpret_cast<const float4*>(act + (t << 7) + ((cb ^ ck) << 2));
            accm = fmaf(Wm[cb * 4 + 0], xv.x, accm);
            accm = fmaf(Wm[cb * 4 + 1], xv.y, accm);
            accm = fmaf(Wm[cb * 4 + 2], xv.z, accm);
            accm = fmaf(Wm[cb * 4 + 3], xv.w, accm);
        }
        out[NPIX + h * WW + t] = leaky(accm + bcl4[h * 257 + 256]);
    }
}

__global__ __launch_bounds__(256) void kB(
    const __hip_bfloat16* __restrict__ xr, const int* __restrict__ ind,
    const float* __restrict__ Wcm2, const float* __restrict__ bcm2,
    const float* __restrict__ Wcm3, const float* __restrict__ bcm3,
    float* __restrict__ out)
{
    const int gwave = (int)((blockIdx.x * blockDim.x + threadIdx.x) >> 6);
    const int lane = threadIdx.x & 63;
    const int nwave = (int)(gridDim.x * (blockDim.x >> 6));

    for (int n = gwave; n < NPIX; n += nwave) {
        const int h_o = n % HH, w_o = n / HH;   // xr source & output position (w-major flat)
        const int h_i = n / WW, w_i = n % WW;   // index-gather position (h-major flat)
        const int ig = ind[h_i * WW + w_i];
        const int sc = (ig >> 4) + (h_i << 4);
        const int rr = ig + (h_i << 8);

        const __hip_bfloat16* xp = xr + (size_t)(h_o * WW + w_o) * 256;
        const float* Wp = Wcm2 + (size_t)sc * 2048;

        float acc[8];
#pragma unroll
        for (int o = 0; o < 8; ++o) acc[o] = 0.f;

        const int c0 = lane * 4;
        const ushort4 xv4 = *(const ushort4*)((const unsigned short*)xp + c0);
        float xf[4];
        xf[0] = __uint_as_float((unsigned int)xv4.x << 16);
        xf[1] = __uint_as_float((unsigned int)xv4.y << 16);
        xf[2] = __uint_as_float((unsigned int)xv4.z << 16);
        xf[3] = __uint_as_float((unsigned int)xv4.w << 16);

#pragma unroll
        for (int i = 0; i < 4; ++i) {
            const float4* wrow = (const float4*)&Wp[(c0 + i) * 8];
            const float4 wa = wrow[0];
            const float4 wb_ = wrow[1];
            const float x = xf[i];
            acc[0] += x * wa.x;  acc[1] += x * wa.y;  acc[2] += x * wa.z;  acc[3] += x * wa.w;
            acc[4] += x * wb_.x; acc[5] += x * wb_.y; acc[6] += x * wb_.z; acc[7] += x * wb_.w;
        }
#pragma unroll
        for (int o = 0; o < 8; ++o) {
            float v = acc[o];
#pragma unroll
            for (int d = 32; d > 0; d >>= 1) v += __shfl_xor(v, d, 64);
            acc[o] = v;
        }
        float r = bcm3[rr];
        const float* b2 = bcm2 + (size_t)sc * 8;
        const float* w3 = Wcm3 + (size_t)rr * 8;
#pragma unroll
        for (int o = 0; o < 8; ++o) {
            const float y = leaky(acc[o] + b2[o]);
            r += y * w3[o];
        }
        if (lane == 0) {
            const float iv = (float)ind[h_o * WW + w_o];
            out[h_o * WW + w_o] = (iv + r) * (1.0f / 256.0f);
        }
    }
}

extern "C" void kernel_launch(void* const* d_in, const int* in_sizes, int n_in,
                              void* d_out, int out_size, void* d_ws, size_t ws_size,
                              hipStream_t stream)
{
    const float* x_in  = (const float*)d_in[0];
    const float* Wcl1  = (const float*)d_in[1];
    const float* bcl1  = (const float*)d_in[2];
    const float* Wcl2  = (const float*)d_in[3];
    const float* bcl2  = (const float*)d_in[4];
    const float* Wcl3  = (const float*)d_in[5];
    const float* bcl3  = (const float*)d_in[6];
    const float* Wcl4  = (const float*)d_in[7];
    const float* bcl4  = (const float*)d_in[8];
    const float* Wreg1 = (const float*)d_in[9];
    const float* breg1 = (const float*)d_in[10];
    const float* Wcm2  = (const float*)d_in[11];
    const float* bcm2  = (const float*)d_in[12];
    const float* Wcm3  = (const float*)d_in[13];
    const float* bcm3  = (const float*)d_in[14];

    float* out = (float*)d_out;

    // workspace: x_r as bf16 [448][160][256], then ind int32 [448*160]
    __hip_bfloat16* xr = (__hip_bfloat16*)d_ws;
    int* ind = (int*)((char*)d_ws + (size_t)NPIX * 256 * sizeof(__hip_bfloat16));

    kA<<<dim3(HH), dim3(512), 0, stream>>>(x_in, Wcl1, bcl1, Wcl2, bcl2, Wcl3, bcl3,
                                           Wcl4, bcl4, Wreg1, breg1, xr, ind, out);
    kB<<<dim3(1792), dim3(256), 0, stream>>>(xr, ind, Wcm2, bcm2, Wcm3, bcm3, out);
}

// Round 4
// 635.543 us; speedup vs baseline: 1.7899x; 1.7899x over previous
//
#include <hip/hip_runtime.h>
#include <hip/hip_bf16.h>

#define HH 448
#define WW 160
#define NPIX (HH*WW)

typedef unsigned long long u64;

__device__ __forceinline__ float leaky(float v) { return v >= 0.f ? v : 0.01f * v; }

// 16 wave-uniform output rows x 3 cols/lane, K=128.
// Weights: wave-uniform addresses -> scalar s_load path (SGPR broadcast, free of LDS/VMEM).
// x: LDS b32 reads at lane-distinct cols (act stored [ch][col], 160%32==0 -> 2-way/broadcast, free).
// FMA order per output: ascending c — bitwise-matches the verified kernels.
__device__ __forceinline__ void gemm16x3(const float* __restrict__ act,
                                         const float* __restrict__ Wrow,
                                         int c0, int c1, int c2, float acc[16][3])
{
#pragma unroll
    for (int r = 0; r < 16; ++r) { acc[r][0] = 0.f; acc[r][1] = 0.f; acc[r][2] = 0.f; }

#pragma unroll 1
    for (int s = 0; s < 8; ++s) {
        float xa[16], xb[16], xc[16];
#pragma unroll
        for (int cc = 0; cc < 16; ++cc) {
            const float* ar = act + (s * 16 + cc) * WW;
            xa[cc] = ar[c0]; xb[cc] = ar[c1]; xc[cc] = ar[c2];
        }
#pragma unroll
        for (int r = 0; r < 16; ++r) {
            const float4* wp = reinterpret_cast<const float4*>(Wrow + r * 128 + s * 16);
            const float4 w0 = wp[0], w1 = wp[1], w2 = wp[2], w3 = wp[3];
            const float wreg[16] = { w0.x, w0.y, w0.z, w0.w, w1.x, w1.y, w1.z, w1.w,
                                     w2.x, w2.y, w2.z, w2.w, w3.x, w3.y, w3.z, w3.w };
#pragma unroll
            for (int cc = 0; cc < 16; ++cc) {
                acc[r][0] = fmaf(wreg[cc], xa[cc], acc[r][0]);
                acc[r][1] = fmaf(wreg[cc], xb[cc], acc[r][1]);
                acc[r][2] = fmaf(wreg[cc], xc[cc], acc[r][2]);
            }
        }
    }
}

__device__ __forceinline__ u64 packKey(float m, int r) {
    unsigned u = __float_as_uint(m);
    u = (u & 0x80000000u) ? ~u : (u | 0x80000000u);   // monotone f32 -> u32
    return ((u64)u << 32) | (unsigned)(255 - r);       // ties -> lowest idx
}

__global__ __launch_bounds__(512, 2) void kA(
    const float* __restrict__ x_in,
    const float* __restrict__ Wcl1, const float* __restrict__ bcl1,
    const float* __restrict__ Wcl2, const float* __restrict__ bcl2,
    const float* __restrict__ Wcl3, const float* __restrict__ bcl3,
    const float* __restrict__ Wcl4, const float* __restrict__ bcl4,
    const float* __restrict__ Wreg1, const float* __restrict__ breg1,
    __hip_bfloat16* __restrict__ xr, int* __restrict__ ind, float* __restrict__ out)
{
    __shared__ float actf[128 * WW];   // 80 KB, [ch][col] activations (in-place per layer)
    __shared__ u64 argb[WW];           // packed (value, 255-idx) argmax

    const int h = blockIdx.x;
    const int t = threadIdx.x;
    const int wvid = __builtin_amdgcn_readfirstlane((int)(threadIdx.x >> 6));  // wave 0..7, uniform
    const int l = t & 63;
    const int c0 = l;                  // col pass 0: 0..63
    const int c1 = 64 + l;             // col pass 1: 64..127
    const int c2 = 128 + (l & 31);     // col pass 2: 128..159 (half-wave duplicated, benign)

    if (t < WW) argb[t] = 0ull;

    // ---- stage x: act[c][w] = x_in[c][h][w] (natural layout, contiguous copy) ----
    {
        const float4* xg = reinterpret_cast<const float4*>(x_in);
        float4* af = reinterpret_cast<float4*>(actf);
#pragma unroll
        for (int k = 0; k < 10; ++k) {
            const int fi = t + (k << 9);          // 0..5119 float4s
            const int c = fi / 40, wq = fi - c * 40;
            af[fi] = xg[((size_t)c * HH + h) * 40 + wq];
        }
    }
    __syncthreads();

    // ---- reg1: 256 rows = 2 passes x (8 waves * 16 rows); bf16 out, no act writes ----
    {
        const float* W1 = Wreg1 + (size_t)h * 32768;
        const float* b1 = breg1 + h * 256;
#pragma unroll 1
        for (int p = 0; p < 2; ++p) {
            const int rbase = p * 128 + wvid * 16;
            float acc[16][3];
            gemm16x3(actf, W1 + rbase * 128, c0, c1, c2, acc);
            const int cols[3] = { c0, c1, c2 };
#pragma unroll
            for (int j = 0; j < 3; ++j) {
                alignas(16) unsigned short us[16];
#pragma unroll
                for (int r = 0; r < 16; ++r) {
                    __hip_bfloat16 bv = __float2bfloat16(leaky(acc[r][j] + b1[rbase + r]));
                    us[r] = *reinterpret_cast<const unsigned short*>(&bv);
                }
                uint4* dst = reinterpret_cast<uint4*>(
                    xr + (((size_t)(h * WW + cols[j])) << 8) + rbase);
                dst[0] = reinterpret_cast<const uint4*>(us)[0];
                dst[1] = reinterpret_cast<const uint4*>(us)[1];
            }
        }
    }

    // ---- cl1..cl3: rows = wvid*16..+15, in-place act update ----
#pragma unroll 1
    for (int L = 0; L < 3; ++L) {
        const float* W = (L == 0) ? Wcl1 + (size_t)h * 16384
                       : (L == 1) ? Wcl2 + (size_t)h * 16384
                                  : Wcl3 + (size_t)h * 16384;
        const float* b = (L == 0) ? bcl1 + (h << 7)
                       : (L == 1) ? bcl2 + (h << 7)
                                  : bcl3 + (h << 7);
        const int rbase = wvid * 16;
        float acc[16][3];
        gemm16x3(actf, W + rbase * 128, c0, c1, c2, acc);
        float bb[16];
#pragma unroll
        for (int r = 0; r < 16; ++r) bb[r] = b[rbase + r];
        __syncthreads();               // all act reads done
#pragma unroll
        for (int r = 0; r < 16; ++r) {
            float* arow = actf + (rbase + r) * WW;
            arow[c0] = leaky(acc[r][0] + bb[r]);
            arow[c1] = leaky(acc[r][1] + bb[r]);
            arow[c2] = leaky(acc[r][2] + bb[r]);
        }
        __syncthreads();
    }

    // ---- cl4: 256 class rows = 2 passes; argmax only (logits never stored) ----
    {
        const float* W4 = Wcl4 + (size_t)h * 32896;
        const float* b4 = bcl4 + h * 257;
        float mv0 = -3.4e38f, mv1 = -3.4e38f, mv2 = -3.4e38f;
        int mr0 = 0, mr1 = 0, mr2 = 0;
#pragma unroll 1
        for (int p = 0; p < 2; ++p) {
            const int rbase = p * 128 + wvid * 16;
            float acc[16][3];
            gemm16x3(actf, W4 + rbase * 128, c0, c1, c2, acc);
#pragma unroll
            for (int r = 0; r < 16; ++r) {
                const float bv = b4[rbase + r];
                const float v0 = acc[r][0] + bv;   // rows ascending per lane
                const float v1 = acc[r][1] + bv;
                const float v2 = acc[r][2] + bv;
                if (v0 > mv0) { mv0 = v0; mr0 = rbase + r; }
                if (v1 > mv1) { mv1 = v1; mr1 = rbase + r; }
                if (v2 > mv2) { mv2 = v2; mr2 = rbase + r; }
            }
        }
        atomicMax(&argb[c0], packKey(mv0, mr0));
        atomicMax(&argb[c1], packKey(mv1, mr1));
        atomicMax(&argb[c2], packKey(mv2, mr2));
    }
    __syncthreads();

    // ---- finalize: ind + mask row (act still holds cl3 output) ----
    if (t < WW) {
        const u64 k = argb[t];
        ind[h * WW + t] = 255 - (int)(k & 0xFFu);
        const float* Wm = Wcl4 + (size_t)h * 32896 + 32768;   // class row 256
        float accm = 0.f;
#pragma unroll 8
        for (int c = 0; c < 128; ++c) accm = fmaf(Wm[c], actf[c * WW + t], accm);
        out[NPIX + h * WW + t] = leaky(accm + bcl4[h * 257 + 256]);
    }
}

__global__ __launch_bounds__(256) void kB(
    const __hip_bfloat16* __restrict__ xr, const int* __restrict__ ind,
    const float* __restrict__ Wcm2, const float* __restrict__ bcm2,
    const float* __restrict__ Wcm3, const float* __restrict__ bcm3,
    float* __restrict__ out)
{
    const int gwave = (int)((blockIdx.x * blockDim.x + threadIdx.x) >> 6);
    const int lane = threadIdx.x & 63;
    const int nwave = (int)(gridDim.x * (blockDim.x >> 6));

    for (int n = gwave; n < NPIX; n += nwave) {
        const int h_o = n % HH, w_o = n / HH;   // xr source & output position (w-major flat)
        const int h_i = n / WW, w_i = n % WW;   // index-gather position (h-major flat)
        const int ig = ind[h_i * WW + w_i];
        const int sc = (ig >> 4) + (h_i << 4);
        const int rr = ig + (h_i << 8);

        const __hip_bfloat16* xp = xr + (size_t)(h_o * WW + w_o) * 256;
        const float* Wp = Wcm2 + (size_t)sc * 2048;

        float acc[8];
#pragma unroll
        for (int o = 0; o < 8; ++o) acc[o] = 0.f;

        const int c0 = lane * 4;
        const ushort4 xv4 = *(const ushort4*)((const unsigned short*)xp + c0);
        float xf[4];
        xf[0] = __uint_as_float((unsigned int)xv4.x << 16);
        xf[1] = __uint_as_float((unsigned int)xv4.y << 16);
        xf[2] = __uint_as_float((unsigned int)xv4.z << 16);
        xf[3] = __uint_as_float((unsigned int)xv4.w << 16);

#pragma unroll
        for (int i = 0; i < 4; ++i) {
            const float4* wrow = (const float4*)&Wp[(c0 + i) * 8];
            const float4 wa = wrow[0];
            const float4 wb_ = wrow[1];
            const float x = xf[i];
            acc[0] += x * wa.x;  acc[1] += x * wa.y;  acc[2] += x * wa.z;  acc[3] += x * wa.w;
            acc[4] += x * wb_.x; acc[5] += x * wb_.y; acc[6] += x * wb_.z; acc[7] += x * wb_.w;
        }
#pragma unroll
        for (int o = 0; o < 8; ++o) {
            float v = acc[o];
#pragma unroll
            for (int d = 32; d > 0; d >>= 1) v += __shfl_xor(v, d, 64);
            acc[o] = v;
        }
        float r = bcm3[rr];
        const float* b2 = bcm2 + (size_t)sc * 8;
        const float* w3 = Wcm3 + (size_t)rr * 8;
#pragma unroll
        for (int o = 0; o < 8; ++o) {
            const float y = leaky(acc[o] + b2[o]);
            r += y * w3[o];
        }
        if (lane == 0) {
            const float iv = (float)ind[h_o * WW + w_o];
            out[h_o * WW + w_o] = (iv + r) * (1.0f / 256.0f);
        }
    }
}

extern "C" void kernel_launch(void* const* d_in, const int* in_sizes, int n_in,
                              void* d_out, int out_size, void* d_ws, size_t ws_size,
                              hipStream_t stream)
{
    const float* x_in  = (const float*)d_in[0];
    const float* Wcl1  = (const float*)d_in[1];
    const float* bcl1  = (const float*)d_in[2];
    const float* Wcl2  = (const float*)d_in[3];
    const float* bcl2  = (const float*)d_in[4];
    const float* Wcl3  = (const float*)d_in[5];
    const float* bcl3  = (const float*)d_in[6];
    const float* Wcl4  = (const float*)d_in[7];
    const float* bcl4  = (const float*)d_in[8];
    const float* Wreg1 = (const float*)d_in[9];
    const float* breg1 = (const float*)d_in[10];
    const float* Wcm2  = (const float*)d_in[11];
    const float* bcm2  = (const float*)d_in[12];
    const float* Wcm3  = (const float*)d_in[13];
    const float* bcm3  = (const float*)d_in[14];

    float* out = (float*)d_out;

    // workspace: x_r as bf16 [448][160][256], then ind int32 [448*160]
    __hip_bfloat16* xr = (__hip_bfloat16*)d_ws;
    int* ind = (int*)((char*)d_ws + (size_t)NPIX * 256 * sizeof(__hip_bfloat16));

    kA<<<dim3(HH), dim3(512), 0, stream>>>(x_in, Wcl1, bcl1, Wcl2, bcl2, Wcl3, bcl3,
                                           Wcl4, bcl4, Wreg1, breg1, xr, ind, out);
    kB<<<dim3(1792), dim3(256), 0, stream>>>(xr, ind, Wcm2, bcm2, Wcm3, bcm3, out);
}

// Round 5
// 395.368 us; speedup vs baseline: 2.8772x; 1.6075x over previous
//
#include <hip/hip_runtime.h>
#include <hip/hip_bf16.h>

#define HH 448
#define WW 160
#define NPIX (HH*WW)

typedef unsigned long long u64;

__device__ __forceinline__ float leaky(float v) { return v >= 0.f ? v : 0.01f * v; }

__device__ __forceinline__ u64 packKey(float m, int r) {
    unsigned u = __float_as_uint(m);
    u = (u & 0x80000000u) ? ~u : (u | 0x80000000u);   // monotone f32 -> u32
    return ((u64)u << 32) | (unsigned)(255 - r);       // ties -> lowest idx
}

// act: logical (w, c) -> phys float idx; block swizzle (c/4)^(w&31) within the w-row.
__device__ __forceinline__ int actIdx(int w, int c) {
    return (w << 7) + ((((c >> 2) ^ (w & 31))) << 2) + (c & 3);
}

// wbuf: logical (r, c) -> phys float4-block ((c>>2) + (r>>3)) & 31 within the r-row.
// Stage from global coalesced: phys f4 slot fi=(r,blk) sources logical blk-(r>>3).
__device__ __forceinline__ void stageW(float* wbuf, const float* __restrict__ Wg, int t) {
    const float4* g4 = reinterpret_cast<const float4*>(Wg);
    float4* w4 = reinterpret_cast<float4*>(wbuf);
    float4 tmp[16];
#pragma unroll
    for (int k = 0; k < 16; ++k) {
        const int fi = t + (k << 8);            // 0..4095
        const int r = fi >> 5, blk = fi & 31;
        tmp[k] = g4[(r << 5) + ((blk - (r >> 3)) & 31)];
    }
#pragma unroll
    for (int k = 0; k < 16; ++k) w4[t + (k << 8)] = tmp[k];
}

// Thread tile: 8 rows (rbase..+7) x 10 cols (cg+16k). Both operands LDS.
// Per cb: 10 x-b128 (2-way/bcast, free) + 8 w-b128 (4-addr bcast, conflict-free) / 320 fmaf.
// FMA order per output: cb ascending, .x.y.z.w — bitwise-matches all verified rounds.
__device__ __forceinline__ void gemmRJ(const float* actf, const float* wbuf,
                                       const int colb[10], const int colk[10],
                                       int rg, int rbase, float acc[8][10])
{
    const float4* a4 = reinterpret_cast<const float4*>(actf);
    const float4* w4 = reinterpret_cast<const float4*>(wbuf);
#pragma unroll
    for (int a = 0; a < 8; ++a)
#pragma unroll
        for (int k = 0; k < 10; ++k) acc[a][k] = 0.f;

#pragma unroll 2
    for (int cb = 0; cb < 32; ++cb) {
        float4 xv[10];
#pragma unroll
        for (int k = 0; k < 10; ++k) xv[k] = a4[colb[k] + (cb ^ colk[k])];
        float4 wv[8];
#pragma unroll
        for (int a = 0; a < 8; ++a) wv[a] = w4[((rbase + a) << 5) + ((cb + rg) & 31)];
#pragma unroll
        for (int a = 0; a < 8; ++a)
#pragma unroll
            for (int k = 0; k < 10; ++k) {
                acc[a][k] = fmaf(wv[a].x, xv[k].x, acc[a][k]);
                acc[a][k] = fmaf(wv[a].y, xv[k].y, acc[a][k]);
                acc[a][k] = fmaf(wv[a].z, xv[k].z, acc[a][k]);
                acc[a][k] = fmaf(wv[a].w, xv[k].w, acc[a][k]);
            }
    }
}

__global__ __launch_bounds__(256, 1) void kA(
    const float* __restrict__ x_in,
    const float* __restrict__ Wcl1, const float* __restrict__ bcl1,
    const float* __restrict__ Wcl2, const float* __restrict__ bcl2,
    const float* __restrict__ Wcl3, const float* __restrict__ bcl3,
    const float* __restrict__ Wcl4, const float* __restrict__ bcl4,
    const float* __restrict__ Wreg1, const float* __restrict__ breg1,
    __hip_bfloat16* __restrict__ xr, int* __restrict__ ind, float* __restrict__ out)
{
    __shared__ float actf[WW * 128];    // 80 KB swizzled [w][c] activations (in-place)
    __shared__ float wbuf[128 * 128];   // 64 KB swizzled current-layer weights
    __shared__ u64 argb[WW];

    const int h = blockIdx.x;
    const int t = threadIdx.x;
    const int rg = t >> 4;        // 0..15 row group (8 rows)
    const int cg = t & 15;        // 0..15 col group (cols cg+16k)
    const int rbase = rg << 3;

    int colb[10], colk[10];
#pragma unroll
    for (int k = 0; k < 10; ++k) { const int w = cg + (k << 4); colb[k] = w << 5; colk[k] = w & 31; }

    if (t < WW) argb[t] = 0ull;

    // ---- stage x: x_in[c][h][*] -> act (transpose + swizzle), coalesced reads ----
    {
        const float4* xg = reinterpret_cast<const float4*>(x_in);
#pragma unroll
        for (int k = 0; k < 20; ++k) {
            const int fi = t + (k << 8);          // 0..5119
            const int c = fi / 40, wq = fi - c * 40;
            const float4 v = xg[c * 17920 + h * 40 + wq];
            const int w0 = wq << 2;
            actf[actIdx(w0 + 0, c)] = v.x;
            actf[actIdx(w0 + 1, c)] = v.y;
            actf[actIdx(w0 + 2, c)] = v.z;
            actf[actIdx(w0 + 3, c)] = v.w;
        }
    }
    stageW(wbuf, Wreg1 + (size_t)h * 32768, t);
    __syncthreads();

    // ---- P0/P1: reg1 rows p*128.., bf16 out ----
#pragma unroll 1
    for (int p = 0; p < 2; ++p) {
        float acc[8][10];
        gemmRJ(actf, wbuf, colb, colk, rg, rbase, acc);
        const float* bp = breg1 + h * 256 + (p << 7) + rbase;
        float bb[8];
#pragma unroll
        for (int a = 0; a < 8; ++a) bb[a] = bp[a];
#pragma unroll
        for (int k = 0; k < 10; ++k) {
            const int w = cg + (k << 4);
            alignas(16) unsigned short us[8];
#pragma unroll
            for (int a = 0; a < 8; ++a) {
                __hip_bfloat16 bv = __float2bfloat16(leaky(acc[a][k] + bb[a]));
                us[a] = *reinterpret_cast<const unsigned short*>(&bv);
            }
            *reinterpret_cast<uint4*>(xr + (((size_t)(h * WW + w)) << 8) + (p << 7) + rbase) =
                *reinterpret_cast<const uint4*>(us);
        }
        __syncthreads();
        stageW(wbuf, (p == 0) ? Wreg1 + (size_t)h * 32768 + 16384
                              : Wcl1 + (size_t)h * 16384, t);
        __syncthreads();
    }

    // ---- P2..P4: cl1..cl3 in-place act update ----
#pragma unroll 1
    for (int L = 0; L < 3; ++L) {
        const float* b = (L == 0) ? bcl1 + (h << 7)
                       : (L == 1) ? bcl2 + (h << 7)
                                  : bcl3 + (h << 7);
        const float* Wnext = (L == 0) ? Wcl2 + (size_t)h * 16384
                           : (L == 1) ? Wcl3 + (size_t)h * 16384
                                      : Wcl4 + (size_t)h * 32896;
        float acc[8][10];
        gemmRJ(actf, wbuf, colb, colk, rg, rbase, acc);
        float bb[8];
#pragma unroll
        for (int a = 0; a < 8; ++a) bb[a] = b[rbase + a];
        __syncthreads();               // all act/wbuf reads done
#pragma unroll
        for (int k = 0; k < 10; ++k) {
            const int w = cg + (k << 4);
            float4 lo, hi;
            lo.x = leaky(acc[0][k] + bb[0]); lo.y = leaky(acc[1][k] + bb[1]);
            lo.z = leaky(acc[2][k] + bb[2]); lo.w = leaky(acc[3][k] + bb[3]);
            hi.x = leaky(acc[4][k] + bb[4]); hi.y = leaky(acc[5][k] + bb[5]);
            hi.z = leaky(acc[6][k] + bb[6]); hi.w = leaky(acc[7][k] + bb[7]);
            const int wk = w & 31;
            *reinterpret_cast<float4*>(actf + (w << 7) + ((((rg << 1)    ) ^ wk) << 2)) = lo;
            *reinterpret_cast<float4*>(actf + (w << 7) + ((((rg << 1) | 1) ^ wk) << 2)) = hi;
        }
        stageW(wbuf, Wnext, t);
        __syncthreads();
    }

    // ---- P5/P6: cl4 argmax (rows 0-127, then 128-255), logits never stored ----
    {
        const float* b4 = bcl4 + h * 257;
        float mv[10]; int mr[10];
#pragma unroll
        for (int k = 0; k < 10; ++k) { mv[k] = -3.4e38f; mr[k] = 0; }
#pragma unroll 1
        for (int p = 0; p < 2; ++p) {
            float acc[8][10];
            gemmRJ(actf, wbuf, colb, colk, rg, rbase, acc);
            const int roff = (p << 7) + rbase;
            float bb[8];
#pragma unroll
            for (int a = 0; a < 8; ++a) bb[a] = b4[roff + a];
#pragma unroll
            for (int k = 0; k < 10; ++k)
#pragma unroll
                for (int a = 0; a < 8; ++a) {
                    const float v = acc[a][k] + bb[a];   // rows ascending per thread
                    if (v > mv[k]) { mv[k] = v; mr[k] = roff + a; }
                }
            if (p == 0) {
                __syncthreads();
                stageW(wbuf, Wcl4 + (size_t)h * 32896 + 16384, t);
                __syncthreads();
            }
        }
#pragma unroll
        for (int k = 0; k < 10; ++k)
            atomicMax(&argb[cg + (k << 4)], packKey(mv[k], mr[k]));
    }
    __syncthreads();

    // ---- finalize: ind + mask row (act still holds cl3 output) ----
    if (t < WW) {
        const u64 k = argb[t];
        ind[h * WW + t] = 255 - (int)(k & 0xFFu);
        const float* Wm = Wcl4 + (size_t)h * 32896 + 32768;   // class row 256
        float accm = 0.f;
#pragma unroll 8
        for (int c = 0; c < 128; ++c) accm = fmaf(Wm[c], actf[actIdx(t, c)], accm);
        out[NPIX + h * WW + t] = leaky(accm + bcl4[h * 257 + 256]);
    }
}

__global__ __launch_bounds__(256) void kB(
    const __hip_bfloat16* __restrict__ xr, const int* __restrict__ ind,
    const float* __restrict__ Wcm2, const float* __restrict__ bcm2,
    const float* __restrict__ Wcm3, const float* __restrict__ bcm3,
    float* __restrict__ out)
{
    const int gwave = (int)((blockIdx.x * blockDim.x + threadIdx.x) >> 6);
    const int lane = threadIdx.x & 63;
    const int nwave = (int)(gridDim.x * (blockDim.x >> 6));

    for (int n = gwave; n < NPIX; n += nwave) {
        const int h_o = n % HH, w_o = n / HH;   // xr source & output position (w-major flat)
        const int h_i = n / WW, w_i = n % WW;   // index-gather position (h-major flat)
        const int ig = ind[h_i * WW + w_i];
        const int sc = (ig >> 4) + (h_i << 4);
        const int rr = ig + (h_i << 8);

        const __hip_bfloat16* xp = xr + (size_t)(h_o * WW + w_o) * 256;
        const float* Wp = Wcm2 + (size_t)sc * 2048;

        float acc[8];
#pragma unroll
        for (int o = 0; o < 8; ++o) acc[o] = 0.f;

        const int c0 = lane * 4;
        const ushort4 xv4 = *(const ushort4*)((const unsigned short*)xp + c0);
        float xf[4];
        xf[0] = __uint_as_float((unsigned int)xv4.x << 16);
        xf[1] = __uint_as_float((unsigned int)xv4.y << 16);
        xf[2] = __uint_as_float((unsigned int)xv4.z << 16);
        xf[3] = __uint_as_float((unsigned int)xv4.w << 16);

#pragma unroll
        for (int i = 0; i < 4; ++i) {
            const float4* wrow = (const float4*)&Wp[(c0 + i) * 8];
            const float4 wa = wrow[0];
            const float4 wb_ = wrow[1];
            const float x = xf[i];
            acc[0] += x * wa.x;  acc[1] += x * wa.y;  acc[2] += x * wa.z;  acc[3] += x * wa.w;
            acc[4] += x * wb_.x; acc[5] += x * wb_.y; acc[6] += x * wb_.z; acc[7] += x * wb_.w;
        }
#pragma unroll
        for (int o = 0; o < 8; ++o) {
            float v = acc[o];
#pragma unroll
            for (int d = 32; d > 0; d >>= 1) v += __shfl_xor(v, d, 64);
            acc[o] = v;
        }
        float r = bcm3[rr];
        const float* b2 = bcm2 + (size_t)sc * 8;
        const float* w3 = Wcm3 + (size_t)rr * 8;
#pragma unroll
        for (int o = 0; o < 8; ++o) {
            const float y = leaky(acc[o] + b2[o]);
            r += y * w3[o];
        }
        if (lane == 0) {
            const float iv = (float)ind[h_o * WW + w_o];
            out[h_o * WW + w_o] = (iv + r) * (1.0f / 256.0f);
        }
    }
}

extern "C" void kernel_launch(void* const* d_in, const int* in_sizes, int n_in,
                              void* d_out, int out_size, void* d_ws, size_t ws_size,
                              hipStream_t stream)
{
    const float* x_in  = (const float*)d_in[0];
    const float* Wcl1  = (const float*)d_in[1];
    const float* bcl1  = (const float*)d_in[2];
    const float* Wcl2  = (const float*)d_in[3];
    const float* bcl2  = (const float*)d_in[4];
    const float* Wcl3  = (const float*)d_in[5];
    const float* bcl3  = (const float*)d_in[6];
    const float* Wcl4  = (const float*)d_in[7];
    const float* bcl4  = (const float*)d_in[8];
    const float* Wreg1 = (const float*)d_in[9];
    const float* breg1 = (const float*)d_in[10];
    const float* Wcm2  = (const float*)d_in[11];
    const float* bcm2  = (const float*)d_in[12];
    const float* Wcm3  = (const float*)d_in[13];
    const float* bcm3  = (const float*)d_in[14];

    float* out = (float*)d_out;

    // workspace: x_r as bf16 [448][160][256], then ind int32 [448*160]
    __hip_bfloat16* xr = (__hip_bfloat16*)d_ws;
    int* ind = (int*)((char*)d_ws + (size_t)NPIX * 256 * sizeof(__hip_bfloat16));

    kA<<<dim3(HH), dim3(256), 0, stream>>>(x_in, Wcl1, bcl1, Wcl2, bcl2, Wcl3, bcl3,
                                           Wcl4, bcl4, Wreg1, breg1, xr, ind, out);
    kB<<<dim3(1792), dim3(256), 0, stream>>>(xr, ind, Wcm2, bcm2, Wcm3, bcm3, out);
}